// Round 1
// baseline (1166.631 us; speedup 1.0000x reference)
//
#include <hip/hip_runtime.h>
#include <math.h>

// Problem constants (B=1)
#define S_LEN   4096
#define D_MODEL 768
#define N_HEAD  12
#define H_DIM   64

// ============================================================================
// GEMM: C[M x N] = A[M x K] * W[N x K]^T (+ optional bias), fp32 row-major.
// BM=128, BN=64, BK=32, 256 threads, 8x4 microtile per thread.
// LDS tiles stored TRANSPOSED ([k][m], [k][n]) so the inner-loop float4 reads
// run along the contiguous M/N dim -> <=2-way bank aliasing (free).
// ============================================================================
__device__ __forceinline__ void gemm_body(const float* __restrict__ A,
                                          const float* __restrict__ W,
                                          const float* __restrict__ bias,
                                          float* __restrict__ C,
                                          int K, int N,
                                          int rowbase, int colbase) {
  const int BK = 32;
  __shared__ float At[32][128 + 4];  // [k][m], stride 132 (16B-aligned rows)
  __shared__ float Wt[32][64 + 4];   // [k][n], stride 68

  const int tid  = threadIdx.x;
  const int trow = tid >> 4;   // 0..15 -> rows trow*8 .. +7
  const int tcol = tid & 15;   // 0..15 -> cols tcol*4 .. +3

  float acc[8][4];
#pragma unroll
  for (int i = 0; i < 8; ++i)
#pragma unroll
    for (int j = 0; j < 4; ++j) acc[i][j] = 0.f;

  for (int k0 = 0; k0 < K; k0 += BK) {
    // Load A tile 128x32 (1024 float4, 4 per thread), write transposed.
#pragma unroll
    for (int it = 0; it < 4; ++it) {
      int f = tid + it * 256;
      int r = f >> 3;
      int c4 = (f & 7) * 4;
      float4 v = *reinterpret_cast<const float4*>(
          &A[(size_t)(rowbase + r) * K + k0 + c4]);
      At[c4 + 0][r] = v.x; At[c4 + 1][r] = v.y;
      At[c4 + 2][r] = v.z; At[c4 + 3][r] = v.w;
    }
    // Load W tile 64x32 (512 float4, 2 per thread), write transposed.
#pragma unroll
    for (int it = 0; it < 2; ++it) {
      int f = tid + it * 256;
      int r = f >> 3;
      int c4 = (f & 7) * 4;
      float4 v = *reinterpret_cast<const float4*>(
          &W[(size_t)(colbase + r) * K + k0 + c4]);
      Wt[c4 + 0][r] = v.x; Wt[c4 + 1][r] = v.y;
      Wt[c4 + 2][r] = v.z; Wt[c4 + 3][r] = v.w;
    }
    __syncthreads();

#pragma unroll
    for (int k = 0; k < BK; ++k) {
      float4 a0 = *reinterpret_cast<const float4*>(&At[k][trow * 8]);
      float4 a1 = *reinterpret_cast<const float4*>(&At[k][trow * 8 + 4]);
      float4 w4 = *reinterpret_cast<const float4*>(&Wt[k][tcol * 4]);
      float a[8] = {a0.x, a0.y, a0.z, a0.w, a1.x, a1.y, a1.z, a1.w};
      float w[4] = {w4.x, w4.y, w4.z, w4.w};
#pragma unroll
      for (int i = 0; i < 8; ++i)
#pragma unroll
        for (int j = 0; j < 4; ++j) acc[i][j] += a[i] * w[j];
    }
    __syncthreads();
  }

  float4 bb = make_float4(0.f, 0.f, 0.f, 0.f);
  if (bias) bb = *reinterpret_cast<const float4*>(&bias[colbase + tcol * 4]);
#pragma unroll
  for (int i = 0; i < 8; ++i) {
    int r = rowbase + trow * 8 + i;
    float4 o;
    o.x = acc[i][0] + bb.x;
    o.y = acc[i][1] + bb.y;
    o.z = acc[i][2] + bb.z;
    o.w = acc[i][3] + bb.w;
    *reinterpret_cast<float4*>(&C[(size_t)r * N + colbase + tcol * 4]) = o;
  }
}

// QKV fused: grid.z selects which projection (0:Q(w_q), 1:K(w_k), 2:V(w_v)).
__global__ __launch_bounds__(256)
void gemm_qkv(const float* __restrict__ x,
              const float* __restrict__ wq, const float* __restrict__ wk,
              const float* __restrict__ wv,
              float* __restrict__ Q, float* __restrict__ K,
              float* __restrict__ V) {
  const float* W = (blockIdx.z == 0) ? wq : (blockIdx.z == 1) ? wk : wv;
  float* C       = (blockIdx.z == 0) ? Q  : (blockIdx.z == 1) ? K  : V;
  gemm_body(x, W, nullptr, C, D_MODEL, D_MODEL,
            blockIdx.y * 128, blockIdx.x * 64);
}

// Output projection with bias.
__global__ __launch_bounds__(256)
void gemm_out(const float* __restrict__ ctx, const float* __restrict__ wo,
              const float* __restrict__ bo, float* __restrict__ out) {
  gemm_body(ctx, wo, bo, out, D_MODEL, D_MODEL,
            blockIdx.y * 128, blockIdx.x * 64);
}

// ============================================================================
// Flash attention fwd (causal), fp32. One block = one head x one 64-row
// q-block. 256 threads, 4x4 microtile over the 64x64 S-tile.
// LDS: Qt[d][r] (Q^T), KPs (K^T during QK^T, then P[r][c]), Vs[c][d].
// 3 x 64 x 68 x 4B = 52.2 KB.
// ============================================================================
__global__ __launch_bounds__(256)
void attn_fwd(const float* __restrict__ Q, const float* __restrict__ K,
              const float* __restrict__ V, float* __restrict__ CTX) {
  __shared__ float Qt[64][68];   // [d][r]
  __shared__ float KPs[64][68];  // K^T: [d][c]; later P: [r][c]
  __shared__ float Vs[64][68];   // [c][d]

  const int tid  = threadIdx.x;
  const int trow = tid >> 4;   // 0..15 -> q rows trow*4..+3 (within tile)
  const int tcol = tid & 15;   // 0..15 -> cols tcol*4..+3
  const int qb   = gridDim.x - 1 - blockIdx.x;  // big-work blocks first
  const int h    = blockIdx.y;
  const float NEG = -3.0e38f;

  // Load Q tile once (transposed into LDS).
#pragma unroll
  for (int it = 0; it < 4; ++it) {
    int f  = tid + it * 256;
    int r  = f >> 4;
    int c4 = (f & 15) * 4;
    float4 v = *reinterpret_cast<const float4*>(
        &Q[(size_t)(qb * 64 + r) * D_MODEL + h * H_DIM + c4]);
    Qt[c4 + 0][r] = v.x; Qt[c4 + 1][r] = v.y;
    Qt[c4 + 2][r] = v.z; Qt[c4 + 3][r] = v.w;
  }

  float o[4][4];
  float m[4], l[4];
#pragma unroll
  for (int i = 0; i < 4; ++i) {
    m[i] = NEG; l[i] = 0.f;
#pragma unroll
    for (int j = 0; j < 4; ++j) o[i][j] = 0.f;
  }

  for (int kb = 0; kb <= qb; ++kb) {
    __syncthreads();  // previous PV done with KPs/Vs
    // Load K tile (transposed) and V tile (row-major).
#pragma unroll
    for (int it = 0; it < 4; ++it) {
      int f  = tid + it * 256;
      int r  = f >> 4;
      int c4 = (f & 15) * 4;
      float4 kv = *reinterpret_cast<const float4*>(
          &K[(size_t)(kb * 64 + r) * D_MODEL + h * H_DIM + c4]);
      KPs[c4 + 0][r] = kv.x; KPs[c4 + 1][r] = kv.y;
      KPs[c4 + 2][r] = kv.z; KPs[c4 + 3][r] = kv.w;
      float4 vv = *reinterpret_cast<const float4*>(
          &V[(size_t)(kb * 64 + r) * D_MODEL + h * H_DIM + c4]);
      *reinterpret_cast<float4*>(&Vs[r][c4]) = vv;
    }
    __syncthreads();

    // S = Q K^T for this 64x64 tile.
    float s[4][4];
#pragma unroll
    for (int i = 0; i < 4; ++i)
#pragma unroll
      for (int j = 0; j < 4; ++j) s[i][j] = 0.f;
#pragma unroll
    for (int d = 0; d < 64; ++d) {
      float4 q4 = *reinterpret_cast<const float4*>(&Qt[d][trow * 4]);
      float4 k4 = *reinterpret_cast<const float4*>(&KPs[d][tcol * 4]);
      float qa[4] = {q4.x, q4.y, q4.z, q4.w};
      float ka[4] = {k4.x, k4.y, k4.z, k4.w};
#pragma unroll
      for (int i = 0; i < 4; ++i)
#pragma unroll
        for (int j = 0; j < 4; ++j) s[i][j] += qa[i] * ka[j];
    }

    const bool diag = (kb == qb);
#pragma unroll
    for (int i = 0; i < 4; ++i)
#pragma unroll
      for (int j = 0; j < 4; ++j) {
        float v = s[i][j] * 0.125f;  // 1/sqrt(64)
        if (diag && (tcol * 4 + j > trow * 4 + i)) v = NEG;
        s[i][j] = v;
      }

    // Online softmax (rows owned by 16-lane groups; xor masks 1,2,4,8 stay
    // inside the group).
    float alpha[4];
#pragma unroll
    for (int i = 0; i < 4; ++i) {
      float mloc = fmaxf(fmaxf(s[i][0], s[i][1]), fmaxf(s[i][2], s[i][3]));
#pragma unroll
      for (int off = 8; off >= 1; off >>= 1)
        mloc = fmaxf(mloc, __shfl_xor(mloc, off));
      float mnew = fmaxf(m[i], mloc);
      alpha[i] = __expf(m[i] - mnew);
      float rs = 0.f;
#pragma unroll
      for (int j = 0; j < 4; ++j) {
        float p = __expf(s[i][j] - mnew);
        s[i][j] = p;
        rs += p;
      }
#pragma unroll
      for (int off = 8; off >= 1; off >>= 1) rs += __shfl_xor(rs, off);
      l[i] = l[i] * alpha[i] + rs;
      m[i] = mnew;
#pragma unroll
      for (int j = 0; j < 4; ++j) o[i][j] *= alpha[i];
    }

    __syncthreads();  // everyone done reading KPs as K^T
    // Write P into KPs as [r][c].
#pragma unroll
    for (int i = 0; i < 4; ++i) {
      float4 p4 = make_float4(s[i][0], s[i][1], s[i][2], s[i][3]);
      *reinterpret_cast<float4*>(&KPs[trow * 4 + i][tcol * 4]) = p4;
    }
    __syncthreads();

    // O += P V
#pragma unroll
    for (int c0 = 0; c0 < 64; c0 += 4) {
      float4 p0 = *reinterpret_cast<const float4*>(&KPs[trow * 4 + 0][c0]);
      float4 p1 = *reinterpret_cast<const float4*>(&KPs[trow * 4 + 1][c0]);
      float4 p2 = *reinterpret_cast<const float4*>(&KPs[trow * 4 + 2][c0]);
      float4 p3 = *reinterpret_cast<const float4*>(&KPs[trow * 4 + 3][c0]);
      float4 v0 = *reinterpret_cast<const float4*>(&Vs[c0 + 0][tcol * 4]);
      float4 v1 = *reinterpret_cast<const float4*>(&Vs[c0 + 1][tcol * 4]);
      float4 v2 = *reinterpret_cast<const float4*>(&Vs[c0 + 2][tcol * 4]);
      float4 v3 = *reinterpret_cast<const float4*>(&Vs[c0 + 3][tcol * 4]);
      float pr[4][4] = {{p0.x, p0.y, p0.z, p0.w},
                        {p1.x, p1.y, p1.z, p1.w},
                        {p2.x, p2.y, p2.z, p2.w},
                        {p3.x, p3.y, p3.z, p3.w}};
      float vr[4][4] = {{v0.x, v0.y, v0.z, v0.w},
                        {v1.x, v1.y, v1.z, v1.w},
                        {v2.x, v2.y, v2.z, v2.w},
                        {v3.x, v3.y, v3.z, v3.w}};
#pragma unroll
      for (int i = 0; i < 4; ++i)
#pragma unroll
        for (int cc = 0; cc < 4; ++cc)
#pragma unroll
          for (int j = 0; j < 4; ++j) o[i][j] += pr[i][cc] * vr[cc][j];
    }
  }

  // Normalize and store ctx.
#pragma unroll
  for (int i = 0; i < 4; ++i) {
    float inv = 1.f / l[i];
    float4 ov = make_float4(o[i][0] * inv, o[i][1] * inv,
                            o[i][2] * inv, o[i][3] * inv);
    *reinterpret_cast<float4*>(
        &CTX[(size_t)(qb * 64 + trow * 4 + i) * D_MODEL + h * H_DIM +
             tcol * 4]) = ov;
  }
}

// ============================================================================
extern "C" void kernel_launch(void* const* d_in, const int* in_sizes, int n_in,
                              void* d_out, int out_size, void* d_ws,
                              size_t ws_size, hipStream_t stream) {
  // setup_inputs order: x, w_k, w_q, w_v, w_o, b_o
  const float* x  = (const float*)d_in[0];
  const float* wk = (const float*)d_in[1];
  const float* wq = (const float*)d_in[2];
  const float* wv = (const float*)d_in[3];
  const float* wo = (const float*)d_in[4];
  const float* bo = (const float*)d_in[5];
  float* out = (float*)d_out;

  const size_t n_elem = (size_t)S_LEN * D_MODEL;
  float* Q   = (float*)d_ws;
  float* K   = Q + n_elem;
  float* V   = K + n_elem;
  float* CTX = V + n_elem;

  dim3 blk(256);
  // QKV projections: 12 x 32 x 3 = 1152 blocks.
  gemm_qkv<<<dim3(D_MODEL / 64, S_LEN / 128, 3), blk, 0, stream>>>(
      x, wq, wk, wv, Q, K, V);
  // Attention: 64 q-blocks x 12 heads = 768 blocks.
  attn_fwd<<<dim3(S_LEN / 64, N_HEAD), blk, 0, stream>>>(Q, K, V, CTX);
  // Output projection: 12 x 32 = 384 blocks.
  gemm_out<<<dim3(D_MODEL / 64, S_LEN / 128, 1), blk, 0, stream>>>(
      CTX, wo, bo, out);
}

// Round 2
// 677.840 us; speedup vs baseline: 1.7211x; 1.7211x over previous
//
#include <hip/hip_runtime.h>
#include <math.h>

// Problem constants (B=1)
#define S_LEN   4096
#define D_MODEL 768
#define N_HEAD  12
#define H_DIM   64

typedef __attribute__((ext_vector_type(8))) short short8;
typedef __attribute__((ext_vector_type(4))) float f32x4;

__device__ __forceinline__ unsigned short f2bh(float f) {
  unsigned u = __float_as_uint(f);
  u += 0x7fffu + ((u >> 16) & 1u);  // round-to-nearest-even
  return (unsigned short)(u >> 16);
}
__device__ __forceinline__ float bh2f(unsigned short h) {
  return __uint_as_float(((unsigned)h) << 16);
}

// XOR swizzle for 64-bf16 (128B) LDS rows: spreads the 16B slot across banks.
#define SWZ(row, colByte) ((((row) * 128) + (colByte)) ^ (((row) & 7) << 4))

// ============================================================================
// fp32 GEMM (unchanged from passing baseline): C = A * W^T (+bias)
// ============================================================================
__device__ __forceinline__ void gemm_body(const float* __restrict__ A,
                                          const float* __restrict__ W,
                                          const float* __restrict__ bias,
                                          float* __restrict__ C,
                                          int K, int N,
                                          int rowbase, int colbase) {
  const int BK = 32;
  __shared__ float At[32][128 + 4];
  __shared__ float Wt[32][64 + 4];

  const int tid  = threadIdx.x;
  const int trow = tid >> 4;
  const int tcol = tid & 15;

  float acc[8][4];
#pragma unroll
  for (int i = 0; i < 8; ++i)
#pragma unroll
    for (int j = 0; j < 4; ++j) acc[i][j] = 0.f;

  for (int k0 = 0; k0 < K; k0 += BK) {
#pragma unroll
    for (int it = 0; it < 4; ++it) {
      int f = tid + it * 256;
      int r = f >> 3;
      int c4 = (f & 7) * 4;
      float4 v = *reinterpret_cast<const float4*>(
          &A[(size_t)(rowbase + r) * K + k0 + c4]);
      At[c4 + 0][r] = v.x; At[c4 + 1][r] = v.y;
      At[c4 + 2][r] = v.z; At[c4 + 3][r] = v.w;
    }
#pragma unroll
    for (int it = 0; it < 2; ++it) {
      int f = tid + it * 256;
      int r = f >> 3;
      int c4 = (f & 7) * 4;
      float4 v = *reinterpret_cast<const float4*>(
          &W[(size_t)(colbase + r) * K + k0 + c4]);
      Wt[c4 + 0][r] = v.x; Wt[c4 + 1][r] = v.y;
      Wt[c4 + 2][r] = v.z; Wt[c4 + 3][r] = v.w;
    }
    __syncthreads();

#pragma unroll
    for (int k = 0; k < BK; ++k) {
      float4 a0 = *reinterpret_cast<const float4*>(&At[k][trow * 8]);
      float4 a1 = *reinterpret_cast<const float4*>(&At[k][trow * 8 + 4]);
      float4 w4 = *reinterpret_cast<const float4*>(&Wt[k][tcol * 4]);
      float a[8] = {a0.x, a0.y, a0.z, a0.w, a1.x, a1.y, a1.z, a1.w};
      float wv[4] = {w4.x, w4.y, w4.z, w4.w};
#pragma unroll
      for (int i = 0; i < 8; ++i)
#pragma unroll
        for (int j = 0; j < 4; ++j) acc[i][j] += a[i] * wv[j];
    }
    __syncthreads();
  }

  float4 bb = make_float4(0.f, 0.f, 0.f, 0.f);
  if (bias) bb = *reinterpret_cast<const float4*>(&bias[colbase + tcol * 4]);
#pragma unroll
  for (int i = 0; i < 8; ++i) {
    int r = rowbase + trow * 8 + i;
    float4 o;
    o.x = acc[i][0] + bb.x;
    o.y = acc[i][1] + bb.y;
    o.z = acc[i][2] + bb.z;
    o.w = acc[i][3] + bb.w;
    *reinterpret_cast<float4*>(&C[(size_t)r * N + colbase + tcol * 4]) = o;
  }
}

__global__ __launch_bounds__(256)
void gemm_qkv(const float* __restrict__ x,
              const float* __restrict__ wq, const float* __restrict__ wk,
              const float* __restrict__ wv,
              float* __restrict__ Q, float* __restrict__ K,
              float* __restrict__ V) {
  const float* W = (blockIdx.z == 0) ? wq : (blockIdx.z == 1) ? wk : wv;
  float* C       = (blockIdx.z == 0) ? Q  : (blockIdx.z == 1) ? K  : V;
  gemm_body(x, W, nullptr, C, D_MODEL, D_MODEL,
            blockIdx.y * 128, blockIdx.x * 64);
}

__global__ __launch_bounds__(256)
void gemm_out(const float* __restrict__ ctx, const float* __restrict__ wo,
              const float* __restrict__ bo, float* __restrict__ out) {
  gemm_body(ctx, wo, bo, out, D_MODEL, D_MODEL,
            blockIdx.y * 128, blockIdx.x * 64);
}

// ============================================================================
// Convert fp32 Q,K -> bf16 hi/lo planes (Q pre-scaled by 1/sqrt(64)).
// ============================================================================
__global__ __launch_bounds__(256)
void convert_qk(const float* __restrict__ Qf, const float* __restrict__ Kf,
                unsigned short* __restrict__ Qh, unsigned short* __restrict__ Ql,
                unsigned short* __restrict__ Kh, unsigned short* __restrict__ Kl) {
  const float* src      = blockIdx.z ? Kf : Qf;
  unsigned short* oh    = blockIdx.z ? Kh : Qh;
  unsigned short* ol    = blockIdx.z ? Kl : Ql;
  const float scale     = blockIdx.z ? 1.0f : 0.125f;
  size_t i = ((size_t)blockIdx.x * 256 + threadIdx.x) * 4;
  float4 v = *reinterpret_cast<const float4*>(&src[i]);
  float a0 = v.x * scale, a1 = v.y * scale, a2 = v.z * scale, a3 = v.w * scale;
  ushort4 hv, lv;
  hv.x = f2bh(a0); lv.x = f2bh(a0 - bh2f(hv.x));
  hv.y = f2bh(a1); lv.y = f2bh(a1 - bh2f(hv.y));
  hv.z = f2bh(a2); lv.z = f2bh(a2 - bh2f(hv.z));
  hv.w = f2bh(a3); lv.w = f2bh(a3 - bh2f(hv.w));
  *reinterpret_cast<ushort4*>(&oh[i]) = hv;
  *reinterpret_cast<ushort4*>(&ol[i]) = lv;
}

// V -> transposed [h][d][s] bf16 hi/lo (via LDS 64x64 tile).
__global__ __launch_bounds__(256)
void convert_v(const float* __restrict__ Vf,
               unsigned short* __restrict__ Vth,
               unsigned short* __restrict__ Vtl) {
  __shared__ float tile[64][65];
  const int tid = threadIdx.x;
  const int s0  = blockIdx.x * 64;
  const int h   = blockIdx.y;
#pragma unroll
  for (int it = 0; it < 16; ++it) {
    int idx = tid + it * 256;
    int r = idx >> 6, c = idx & 63;
    tile[r][c] = Vf[(size_t)(s0 + r) * D_MODEL + h * H_DIM + c];
  }
  __syncthreads();
#pragma unroll
  for (int it = 0; it < 16; ++it) {
    int idx = tid + it * 256;
    int d = idx >> 6, sl = idx & 63;
    float x = tile[sl][d];
    unsigned short xh = f2bh(x);
    size_t o = (size_t)(h * H_DIM + d) * S_LEN + s0 + sl;
    Vth[o] = xh;
    Vtl[o] = f2bh(x - bh2f(xh));
  }
}

// ============================================================================
// Flash attention fwd (causal) via bf16x3 MFMA, fp32 online softmax.
// Block: 1 head x 64 q-rows, 4 waves x 16 rows. LDS ~50KB -> 3 blocks/CU.
// ============================================================================
__global__ __launch_bounds__(256)
void attn_mfma(const unsigned short* __restrict__ Qh_g,
               const unsigned short* __restrict__ Ql_g,
               const unsigned short* __restrict__ Kh_g,
               const unsigned short* __restrict__ Kl_g,
               const unsigned short* __restrict__ Vh_g,
               const unsigned short* __restrict__ Vl_g,
               float* __restrict__ CTX) {
  __shared__ __align__(16) unsigned short Kh_s[64 * 64];
  __shared__ __align__(16) unsigned short Kl_s[64 * 64];
  __shared__ __align__(16) unsigned short Vh_s[64 * 64];
  __shared__ __align__(16) unsigned short Vl_s[64 * 64];
  __shared__ unsigned int P_s[4][16 * 68];  // per-wave, packed hi|lo

  char* KhB = (char*)Kh_s;
  char* KlB = (char*)Kl_s;
  char* VhB = (char*)Vh_s;
  char* VlB = (char*)Vl_s;

  const int tid  = threadIdx.x;
  const int lane = tid & 63;
  const int w    = tid >> 6;
  const int qb   = gridDim.x - 1 - blockIdx.x;  // big-work blocks first
  const int h    = blockIdx.y;
  const int lr   = lane & 15;  // row-within-16 (A) / col-within-16 (B,C)
  const int lk   = lane >> 4;  // k-group / C row-group
  const float NEG = -1e30f;

  // ---- Prologue: stage Q tile through K buffers, hoist A-frags to regs ----
#pragma unroll
  for (int p = 0; p < 2; ++p) {
    int id = tid + p * 256;
    int r  = id >> 3;
    int cb = (id & 7) * 16;
    int ce = (id & 7) * 8;
    size_t g = (size_t)(qb * 64 + r) * D_MODEL + h * H_DIM + ce;
    *reinterpret_cast<float4*>(KhB + SWZ(r, cb)) =
        *reinterpret_cast<const float4*>(Qh_g + g);
    *reinterpret_cast<float4*>(KlB + SWZ(r, cb)) =
        *reinterpret_cast<const float4*>(Ql_g + g);
  }
  __syncthreads();
  short8 aqh[2], aql[2];
#pragma unroll
  for (int kc = 0; kc < 2; ++kc) {
    int ao = SWZ(w * 16 + lr, kc * 64 + lk * 16);
    aqh[kc] = *reinterpret_cast<const short8*>(KhB + ao);
    aql[kc] = *reinterpret_cast<const short8*>(KlB + ao);
  }

  f32x4 o[4];
  float m[4], l[4];
#pragma unroll
  for (int t = 0; t < 4; ++t) o[t] = {0.f, 0.f, 0.f, 0.f};
#pragma unroll
  for (int r = 0; r < 4; ++r) { m[r] = NEG; l[r] = 0.f; }

  for (int kt = 0; kt <= qb; ++kt) {
    __syncthreads();  // prior tile's LDS reads done (also covers Q-frag reads)
    // ---- stage K/V tile (reg-staged, swizzled LDS writes) ----
#pragma unroll
    for (int p = 0; p < 2; ++p) {
      int id = tid + p * 256;
      int r  = id >> 3;
      int cb = (id & 7) * 16;
      int ce = (id & 7) * 8;
      size_t gk = (size_t)(kt * 64 + r) * D_MODEL + h * H_DIM + ce;
      size_t gv = (size_t)(h * H_DIM + r) * S_LEN + kt * 64 + ce;
      *reinterpret_cast<float4*>(KhB + SWZ(r, cb)) =
          *reinterpret_cast<const float4*>(Kh_g + gk);
      *reinterpret_cast<float4*>(KlB + SWZ(r, cb)) =
          *reinterpret_cast<const float4*>(Kl_g + gk);
      *reinterpret_cast<float4*>(VhB + SWZ(r, cb)) =
          *reinterpret_cast<const float4*>(Vh_g + gv);
      *reinterpret_cast<float4*>(VlB + SWZ(r, cb)) =
          *reinterpret_cast<const float4*>(Vl_g + gv);
    }
    __syncthreads();

    // ---- S = Q K^T (bf16x3) ----
    f32x4 sacc[4];
#pragma unroll
    for (int t = 0; t < 4; ++t) sacc[t] = {0.f, 0.f, 0.f, 0.f};
#pragma unroll
    for (int kc = 0; kc < 2; ++kc) {
#pragma unroll
      for (int t = 0; t < 4; ++t) {
        int bo = SWZ(t * 16 + lr, kc * 64 + lk * 16);
        short8 bh = *reinterpret_cast<const short8*>(KhB + bo);
        short8 bl = *reinterpret_cast<const short8*>(KlB + bo);
        sacc[t] = __builtin_amdgcn_mfma_f32_16x16x32_bf16(aqh[kc], bh, sacc[t], 0, 0, 0);
        sacc[t] = __builtin_amdgcn_mfma_f32_16x16x32_bf16(aql[kc], bh, sacc[t], 0, 0, 0);
        sacc[t] = __builtin_amdgcn_mfma_f32_16x16x32_bf16(aqh[kc], bl, sacc[t], 0, 0, 0);
      }
    }

    // ---- causal mask on the diagonal tile ----
    if (kt == qb) {
#pragma unroll
      for (int t = 0; t < 4; ++t) {
        int colg = t * 16 + lr;
#pragma unroll
        for (int r = 0; r < 4; ++r) {
          int rowg = w * 16 + lk * 4 + r;
          if (colg > rowg) sacc[t][r] = NEG;
        }
      }
    }

    // ---- online softmax (rows live in 16-lane groups) ----
    float pf[4][4];  // [t][r]
#pragma unroll
    for (int r = 0; r < 4; ++r) {
      float mx = fmaxf(fmaxf(sacc[0][r], sacc[1][r]),
                       fmaxf(sacc[2][r], sacc[3][r]));
      mx = fmaxf(mx, __shfl_xor(mx, 1));
      mx = fmaxf(mx, __shfl_xor(mx, 2));
      mx = fmaxf(mx, __shfl_xor(mx, 4));
      mx = fmaxf(mx, __shfl_xor(mx, 8));
      float mnew  = fmaxf(m[r], mx);
      float alpha = __expf(m[r] - mnew);
      float rs = 0.f;
#pragma unroll
      for (int t = 0; t < 4; ++t) {
        float p = __expf(sacc[t][r] - mnew);
        pf[t][r] = p;
        rs += p;
      }
      rs += __shfl_xor(rs, 1);
      rs += __shfl_xor(rs, 2);
      rs += __shfl_xor(rs, 4);
      rs += __shfl_xor(rs, 8);
      l[r] = l[r] * alpha + rs;
      m[r] = mnew;
#pragma unroll
      for (int t = 0; t < 4; ++t) o[t][r] *= alpha;
    }

    // ---- P -> per-wave LDS (packed hi|lo u32), A-frag friendly layout ----
    unsigned int* pw = P_s[w];
#pragma unroll
    for (int r = 0; r < 4; ++r) {
#pragma unroll
      for (int t = 0; t < 4; ++t) {
        float p = pf[t][r];
        unsigned short ph = f2bh(p);
        unsigned short pl = f2bh(p - bh2f(ph));
        pw[(lk * 4 + r) * 68 + t * 16 + lr] =
            (unsigned)ph | ((unsigned)pl << 16);
      }
    }

    // ---- O += P V (bf16x3) ----
#pragma unroll
    for (int kc = 0; kc < 2; ++kc) {
      const uint4* pp = reinterpret_cast<const uint4*>(
          &pw[lr * 68 + kc * 32 + lk * 8]);
      uint4 u0 = pp[0];
      uint4 u1 = pp[1];
      short8 pah, pal;
      pah[0] = (short)(u0.x & 0xffff); pal[0] = (short)(u0.x >> 16);
      pah[1] = (short)(u0.y & 0xffff); pal[1] = (short)(u0.y >> 16);
      pah[2] = (short)(u0.z & 0xffff); pal[2] = (short)(u0.z >> 16);
      pah[3] = (short)(u0.w & 0xffff); pal[3] = (short)(u0.w >> 16);
      pah[4] = (short)(u1.x & 0xffff); pal[4] = (short)(u1.x >> 16);
      pah[5] = (short)(u1.y & 0xffff); pal[5] = (short)(u1.y >> 16);
      pah[6] = (short)(u1.z & 0xffff); pal[6] = (short)(u1.z >> 16);
      pah[7] = (short)(u1.w & 0xffff); pal[7] = (short)(u1.w >> 16);
#pragma unroll
      for (int t = 0; t < 4; ++t) {
        int bo = SWZ(t * 16 + lr, kc * 64 + lk * 16);
        short8 vh = *reinterpret_cast<const short8*>(VhB + bo);
        short8 vl = *reinterpret_cast<const short8*>(VlB + bo);
        o[t] = __builtin_amdgcn_mfma_f32_16x16x32_bf16(pah, vh, o[t], 0, 0, 0);
        o[t] = __builtin_amdgcn_mfma_f32_16x16x32_bf16(pah, vl, o[t], 0, 0, 0);
        o[t] = __builtin_amdgcn_mfma_f32_16x16x32_bf16(pal, vh, o[t], 0, 0, 0);
      }
    }
  }

  // ---- epilogue: normalize, store ctx ----
  float inv[4];
#pragma unroll
  for (int r = 0; r < 4; ++r) inv[r] = 1.f / l[r];
#pragma unroll
  for (int t = 0; t < 4; ++t)
#pragma unroll
    for (int r = 0; r < 4; ++r)
      CTX[(size_t)(qb * 64 + w * 16 + lk * 4 + r) * D_MODEL + h * H_DIM +
          t * 16 + lr] = o[t][r] * inv[r];
}

// ============================================================================
extern "C" void kernel_launch(void* const* d_in, const int* in_sizes, int n_in,
                              void* d_out, int out_size, void* d_ws,
                              size_t ws_size, hipStream_t stream) {
  // setup_inputs order: x, w_k, w_q, w_v, w_o, b_o
  const float* x  = (const float*)d_in[0];
  const float* wk = (const float*)d_in[1];
  const float* wq = (const float*)d_in[2];
  const float* wv = (const float*)d_in[3];
  const float* wo = (const float*)d_in[4];
  const float* bo = (const float*)d_in[5];
  float* out = (float*)d_out;

  const size_t n_elem = (size_t)S_LEN * D_MODEL;  // 3,145,728
  float* Qf  = (float*)d_ws;
  float* Kf  = Qf + n_elem;
  float* Vf  = Kf + n_elem;
  float* CTX = Vf + n_elem;
  unsigned short* Qh  = (unsigned short*)(CTX + n_elem);
  unsigned short* Ql  = Qh + n_elem;
  unsigned short* Kh  = Ql + n_elem;
  unsigned short* Kl  = Kh + n_elem;
  unsigned short* Vth = Kl + n_elem;
  unsigned short* Vtl = Vth + n_elem;

  dim3 blk(256);
  // QKV projections (fp32, unchanged).
  gemm_qkv<<<dim3(D_MODEL / 64, S_LEN / 128, 3), blk, 0, stream>>>(
      x, wq, wk, wv, Qf, Kf, Vf);
  // Convert to bf16 hi/lo planes.
  convert_qk<<<dim3((unsigned)(n_elem / 4 / 256), 1, 2), blk, 0, stream>>>(
      Qf, Kf, Qh, Ql, Kh, Kl);
  convert_v<<<dim3(S_LEN / 64, N_HEAD), blk, 0, stream>>>(Vf, Vth, Vtl);
  // Attention (bf16x3 MFMA).
  attn_mfma<<<dim3(S_LEN / 64, N_HEAD), blk, 0, stream>>>(
      Qh, Ql, Kh, Kl, Vth, Vtl, CTX);
  // Output projection (fp32, unchanged).
  gemm_out<<<dim3(D_MODEL / 64, S_LEN / 128, 1), blk, 0, stream>>>(
      CTX, wo, bo, out);
}